// Round 6
// baseline (291.240 us; speedup 1.0000x reference)
//
#include <hip/hip_runtime.h>
#include <stdint.h>

#define NPRIOR 8400
#define NB 32
#define NCLS 80
#define KTOP 1000
#define CAP 4096   // power of two REQUIRED (bitonic S = nextpow2(cn) <= CAP)

typedef unsigned long long u64;

// Bit-exact replica of numpy's float32 SIMD exp (Cephes-style, FMA path):
//   numpy/core/src/umath/loops_exponent_log.dispatch.c.src
//   q = rint(x*log2e); r = fma(q,-ln2hi,x); r = fma(q,-ln2lo,r);
//   p = deg-5 FMA poly; p = fma(p, r*r, r) + 1; result = p * 2^q (exact scalef)
__device__ __forceinline__ float exp_np(float x) {
#pragma clang fp contract(off)
    if (x > 88.72283935546875f) return __builtin_huge_valf();
    if (x < -87.3365478515625f) return 0.0f;
    float q = rintf(x * 1.442695040f);          // v_rndne: round-nearest-even
    float r = fmaf(q, -6.93145752e-1f, x);      // hi split (low bits zero)
    r = fmaf(q, -1.42860677e-6f, r);            // lo split
    float p = fmaf(1.9875691500e-4f, r, 1.3981999507e-3f);
    p = fmaf(p, r, 8.3334519073e-3f);
    p = fmaf(p, r, 4.1665795894e-2f);
    p = fmaf(p, r, 1.6666665459e-1f);
    p = fmaf(p, r, 5.0000001201e-1f);
    float r2 = r * r;
    p = fmaf(p, r2, r);
    p = p + 1.0f;
    return ldexpf(p, (int)q);                   // exact 2^q scaling (scalef)
}
// numpy f32 sigmoid: 1/(1+np.exp(-x)), each op f32 CR except the poly exp.
__device__ __forceinline__ float sigm_np(float x) {
#pragma clang fp contract(off)
    float t = exp_np(-x);
    return 1.0f / (1.0f + t);
}

__device__ __forceinline__ void level_of(int n, int& W, int& s, int& loc) {
    if (n < 6400)      { W = 80; s = 8;  loc = n; }
    else if (n < 8000) { W = 40; s = 16; loc = n - 6400; }
    else               { W = 20; s = 32; loc = n - 8000; }
}

// f32 box decode for prior n of image b, matching np f32 op-for-op (no FMA).
__device__ float4 decode32(int b, int n,
                           const float* bb0, const float* bb1, const float* bb2) {
#pragma clang fp contract(off)
    int W, s, loc; level_of(n, W, s, loc);
    const float* bb = (s == 8) ? bb0 : (s == 16) ? bb1 : bb2;
    int hw = W * W;
    int y = loc / W, x = loc - y * W;
    const float* bp = bb + (size_t)b * 4 * hw + y * W + x;
    float fs = (float)s;
    float cx = (float)x * fs, cy = (float)y * fs;   // exact
    float xc = bp[0] * fs + cx;                     // mul, then add (no fma)
    float yc = bp[hw] * fs + cy;
    float wv = exp_np(bp[2 * hw]) * fs;             // np.exp poly, *pow2 exact
    float hv = exp_np(bp[3 * hw]) * fs;
    float wv2 = wv * 0.5f, hv2 = hv * 0.5f;
    float4 r;
    r.x = xc - wv2;
    r.y = yc - hv2;
    r.z = xc + wv2;
    r.w = yc + hv2;
    return r;
}

// ---------------- Kernel A: per-prior score + np-argmax-over-sigmoids ----------------
__global__ void __launch_bounds__(256) score_k(
    const float* __restrict__ cls0, const float* __restrict__ cls1, const float* __restrict__ cls2,
    const float* __restrict__ ob0,  const float* __restrict__ ob1,  const float* __restrict__ ob2,
    float* __restrict__ sc, int* __restrict__ labels)
{
#pragma clang fp contract(off)
    int gid = blockIdx.x * 256 + threadIdx.x;
    if (gid >= NB * NPRIOR) return;
    int b = gid / NPRIOR;
    int n = gid - b * NPRIOR;
    int W, s, loc; level_of(n, W, s, loc);
    const float* cls = (s == 8) ? cls0 : (s == 16) ? cls1 : cls2;
    const float* ob  = (s == 8) ? ob0  : (s == 16) ? ob1  : ob2;
    int hw = W * W;
    int y = loc / W, x = loc - y * W;

    // np.argmax over the SIGMOID values, first-max kept — no monotonicity
    // assumption on the poly exp (it is not guaranteed bitwise monotone).
    const float* cp = cls + (size_t)b * NCLS * hw + y * W + x;
    float tM = sigm_np(cp[0]);
    int lab = 0;
    for (int c = 1; c < NCLS; ++c) {
        float t = sigm_np(cp[(size_t)c * hw]);
        if (t > tM) { tM = t; lab = c; }
    }
    float sObj = sigm_np(ob[(size_t)b * hw + y * W + x]);
    float score = tM * sObj;                  // f32 CR multiply
    bool valid = score >= 0.65f;
    sc[gid] = valid ? score : 0.0f;
    labels[gid] = lab;
}

// ---------------- Kernel B: stable top-K (f32 keys) + f32 decode ----------------
__global__ void __launch_bounds__(256) select_sort(
    const float* __restrict__ sc, const int* __restrict__ labels,
    const float* __restrict__ bb0, const float* __restrict__ bb1, const float* __restrict__ bb2,
    float4* __restrict__ sel_box, float* __restrict__ sel_score,
    int* __restrict__ sel_label, float* __restrict__ mcarr, u64* __restrict__ vmask)
{
#pragma clang fp contract(off)
    __shared__ u64 keys[CAP];
    __shared__ int cnt;
    __shared__ float redbuf[256];
    __shared__ unsigned vbits[32];

    int b = blockIdx.x, tid = threadIdx.x;
    if (tid == 0) cnt = 0;
    if (tid < 32) vbits[tid] = 0u;
    __syncthreads();

    const float* scb = sc + (size_t)b * NPRIOR;
    for (int n = tid; n < NPRIOR; n += 256) {
        float s = scb[n];
        if (s > 0.0f) {
            int p = atomicAdd(&cnt, 1);
            if (p < CAP)
                keys[p] = ((u64)__float_as_uint(s) << 32) | (unsigned)(~(unsigned)n);
        }
    }
    __syncthreads();
    int cn = min(cnt, CAP);
    int S = 1;
    while (S < cn) S <<= 1;
    for (int i = cn + tid; i < S; i += 256) keys[i] = 0ull;
    __syncthreads();

    // bitonic sort desc: score bits desc, index asc (via ~n payload)
    for (int k = 2; k <= S; k <<= 1) {
        for (int j = k >> 1; j > 0; j >>= 1) {
            for (int i = tid; i < S; i += 256) {
                int ixj = i ^ j;
                if (ixj > i) {
                    u64 a = keys[i], c = keys[ixj];
                    bool descB = ((i & k) == 0);
                    if (descB ? (a < c) : (a > c)) { keys[i] = c; keys[ixj] = a; }
                }
            }
            __syncthreads();
        }
    }

    // fewer than K valid -> fill with lowest-index zero-score entries
    if (cn < KTOP) {
        if (tid == 0) {
            int r = cn;
            for (int n = 0; n < NPRIOR && r < KTOP; ++n) {
                if (scb[n] == 0.0f) { keys[r] = (u64)(unsigned)(~(unsigned)n); ++r; }
            }
        }
        __syncthreads();
    }

    const int* labb = labels + (size_t)b * NPRIOR;
    float lmax = 0.0f;
    for (int kk = tid; kk < KTOP; kk += 256) {
        u64 key = keys[kk];
        unsigned n = ~(unsigned)(key & 0xffffffffull);
        float s = __uint_as_float((unsigned)(key >> 32));
        float4 bx = decode32(b, (int)n, bb0, bb1, bb2);
        sel_box[(size_t)b * 1024 + kk] = bx;
        sel_score[(size_t)b * 1024 + kk] = s;
        sel_label[(size_t)b * 1024 + kk] = labb[n];
        if (s > 0.0f) atomicOr(&vbits[kk >> 5], 1u << (kk & 31));
        lmax = fmaxf(lmax, fmaxf(fmaxf(fabsf(bx.x), fabsf(bx.y)),
                                 fmaxf(fabsf(bx.z), fabsf(bx.w))));
    }
    redbuf[tid] = lmax;
    __syncthreads();
    for (int off = 128; off > 0; off >>= 1) {
        if (tid < off) redbuf[tid] = fmaxf(redbuf[tid], redbuf[tid + off]);
        __syncthreads();
    }
    if (tid == 0) mcarr[b] = redbuf[0] + 1.0f;   // max_coord, f32 add
    if (tid < 16)
        vmask[b * 16 + tid] = ((u64)vbits[tid * 2 + 1] << 32) | vbits[tid * 2];
}

// ---------------- Kernel C: f32 IoU suppression bitmask via ballot ----------------
__global__ void __launch_bounds__(256) build_mask(
    const float4* __restrict__ sel_box, const int* __restrict__ sel_label,
    const float* __restrict__ mcarr, u64* __restrict__ mask)
{
#pragma clang fp contract(off)
    __shared__ float4 ob[KTOP];
    __shared__ float ar[KTOP];
    int b = blockIdx.y, chunk = blockIdx.x, tid = threadIdx.x;
    float mc = mcarr[b];
    for (int i = tid; i < KTOP; i += 256) {
        float4 v = sel_box[(size_t)b * 1024 + i];
        float off = (float)sel_label[(size_t)b * 1024 + i] * mc;
        v.x += off; v.y += off; v.z += off; v.w += off;
        ob[i] = v;
        ar[i] = (v.z - v.x) * (v.w - v.y);   // area of OFFSET box (as ref)
    }
    __syncthreads();
    int wave = tid >> 6, lane = tid & 63;
    for (int r = 0; r < 16; ++r) {
        int i = chunk * 64 + wave * 16 + r;
        if (i >= KTOP) continue;
        float4 a = ob[i];
        float aa = ar[i];
        u64* mrow = mask + ((size_t)b * 1024 + i) * 16;
        for (int c = 0; c < 16; ++c) {
            int jj = c * 64 + lane;
            bool pred = false;
            if (jj < KTOP && jj > i) {
                float4 bb = ob[jj];
                float tlx = fmaxf(a.x, bb.x), tly = fmaxf(a.y, bb.y);
                float brx = fminf(a.z, bb.z), bry = fminf(a.w, bb.w);
                float w = fmaxf(brx - tlx, 0.0f), h = fmaxf(bry - tly, 0.0f);
                float inter = w * h;
                float uni = (aa + ar[jj]) - inter;   // same assoc as ref
                float iou = inter / (uni + 1e-6f);
                pred = iou > 0.65f;
            }
            u64 bits = __ballot(pred);
            if (lane == 0) mrow[c] = bits;
        }
    }
}

// ---------------- Kernel D: sequential greedy reduce + output ----------------
__global__ void __launch_bounds__(64) nms_reduce_write(
    const u64* __restrict__ mask, const u64* __restrict__ vmask,
    const float4* __restrict__ sel_box, const float* __restrict__ sel_score,
    const int* __restrict__ sel_label, float* __restrict__ out)
{
    int b = blockIdx.x, t = threadIdx.x;
    bool owner = (t < 16);
    const u64* mrow = mask + ((size_t)b * 1024) * 16 + t;
    u64 vm = owner ? vmask[b * 16 + t] : 0ull;
    u64 remv = 0ull;
    u64 pf[8];
#pragma unroll
    for (int d = 0; d < 8; ++d) pf[d] = owner ? mrow[(size_t)d * 16] : 0ull;
    for (int base = 0; base < KTOP; base += 8) {
#pragma unroll
        for (int u = 0; u < 8; ++u) {
            int i = base + u;
            u64 row = pf[u];
            int nxt = i + 8;
            pf[u] = (owner && nxt < KTOP) ? mrow[(size_t)nxt * 16] : 0ull;
            int w = i >> 6, bit = i & 63;
            u64 rv = __shfl(remv, w);
            u64 vv = __shfl(vm, w);
            if (!((rv >> bit) & 1ull) && ((vv >> bit) & 1ull)) remv |= row;
        }
    }
    __shared__ u64 rem_sh[16], vm_sh[16];
    if (owner) { rem_sh[t] = remv; vm_sh[t] = vm; }
    __syncthreads();

    const size_t selo = (size_t)b * 1024;
    float* lab_o = out + (size_t)NB * KTOP * 5;
    float* keep_o = lab_o + (size_t)NB * KTOP;
    for (int k = t; k < KTOP; k += 64) {
        int w = k >> 6;
        bool fin = ((~rem_sh[w] & vm_sh[w]) >> (k & 63)) & 1ull;
        float4 bx = sel_box[selo + k];
        float s = sel_score[selo + k];
        int lb = sel_label[selo + k];
        size_t o5 = ((size_t)b * KTOP + k) * 5;
        out[o5 + 0] = fin ? bx.x : 0.0f;
        out[o5 + 1] = fin ? bx.y : 0.0f;
        out[o5 + 2] = fin ? bx.z : 0.0f;
        out[o5 + 3] = fin ? bx.w : 0.0f;
        out[o5 + 4] = fin ? s : 0.0f;
        lab_o[b * KTOP + k] = fin ? (float)lb : -1.0f;
        keep_o[b * KTOP + k] = fin ? 1.0f : 0.0f;
    }
}

extern "C" void kernel_launch(void* const* d_in, const int* in_sizes, int n_in,
                              void* d_out, int out_size, void* d_ws, size_t ws_size,
                              hipStream_t stream) {
    const float* cls0 = (const float*)d_in[0];
    const float* cls1 = (const float*)d_in[1];
    const float* cls2 = (const float*)d_in[2];
    const float* bb0  = (const float*)d_in[3];
    const float* bb1  = (const float*)d_in[4];
    const float* bb2  = (const float*)d_in[5];
    const float* ob0  = (const float*)d_in[6];
    const float* ob1  = (const float*)d_in[7];
    const float* ob2  = (const float*)d_in[8];
    float* out = (float*)d_out;

    char* w = (char*)d_ws;
    size_t used = 0;
    auto alloc = [&](size_t bytes) -> void* {
        void* p = (void*)(w + used);
        used += (bytes + 255) & ~(size_t)255;
        return p;
    };
    float* sc        = (float*)alloc((size_t)NB * NPRIOR * 4);
    int* labels      = (int*)alloc((size_t)NB * NPRIOR * 4);
    float4* sel_box  = (float4*)alloc((size_t)NB * 1024 * 16);
    float* sel_score = (float*)alloc((size_t)NB * 1024 * 4);
    int* sel_label   = (int*)alloc((size_t)NB * 1024 * 4);
    float* mcarr     = (float*)alloc((size_t)NB * 4);
    u64* vmask       = (u64*)alloc((size_t)NB * 16 * 8);
    u64* mask        = (u64*)alloc((size_t)NB * 1024 * 16 * 8);

    if (used > ws_size) return;   // OOB-write guard (clean failure, no corruption)

    int total = NB * NPRIOR;
    score_k<<<(total + 255) / 256, 256, 0, stream>>>(
        cls0, cls1, cls2, ob0, ob1, ob2, sc, labels);
    select_sort<<<NB, 256, 0, stream>>>(
        sc, labels, bb0, bb1, bb2, sel_box, sel_score, sel_label, mcarr, vmask);
    build_mask<<<dim3(16, NB), 256, 0, stream>>>(sel_box, sel_label, mcarr, mask);
    nms_reduce_write<<<NB, 64, 0, stream>>>(
        mask, vmask, sel_box, sel_score, sel_label, out);
}

// Round 7
// 194.865 us; speedup vs baseline: 1.4946x; 1.4946x over previous
//
#include <hip/hip_runtime.h>
#include <stdint.h>

#define NPRIOR 8400
#define NB 32
#define NCLS 80
#define KTOP 1000
#define CAP 4096   // power of two REQUIRED (bitonic S = nextpow2(cn) <= CAP)

typedef unsigned long long u64;

// Bit-exact replica of numpy's float32 SIMD exp (Cephes-style, FMA path).
__device__ __forceinline__ float exp_np(float x) {
#pragma clang fp contract(off)
    if (x > 88.72283935546875f) return __builtin_huge_valf();
    if (x < -87.3365478515625f) return 0.0f;
    float q = rintf(x * 1.442695040f);          // v_rndne: round-nearest-even
    float r = fmaf(q, -6.93145752e-1f, x);      // hi split
    r = fmaf(q, -1.42860677e-6f, r);            // lo split
    float p = fmaf(1.9875691500e-4f, r, 1.3981999507e-3f);
    p = fmaf(p, r, 8.3334519073e-3f);
    p = fmaf(p, r, 4.1665795894e-2f);
    p = fmaf(p, r, 1.6666665459e-1f);
    p = fmaf(p, r, 5.0000001201e-1f);
    float r2 = r * r;
    p = fmaf(p, r2, r);
    p = p + 1.0f;
    return ldexpf(p, (int)q);                   // exact 2^q scaling
}
__device__ __forceinline__ float sigm_np(float x) {
#pragma clang fp contract(off)
    float t = exp_np(-x);
    return 1.0f / (1.0f + t);
}

__device__ __forceinline__ void level_of(int n, int& W, int& s, int& loc) {
    if (n < 6400)      { W = 80; s = 8;  loc = n; }
    else if (n < 8000) { W = 40; s = 16; loc = n - 6400; }
    else               { W = 20; s = 32; loc = n - 8000; }
}

__device__ float4 decode32(int b, int n,
                           const float* bb0, const float* bb1, const float* bb2) {
#pragma clang fp contract(off)
    int W, s, loc; level_of(n, W, s, loc);
    const float* bb = (s == 8) ? bb0 : (s == 16) ? bb1 : bb2;
    int hw = W * W;
    int y = loc / W, x = loc - y * W;
    const float* bp = bb + (size_t)b * 4 * hw + y * W + x;
    float fs = (float)s;
    float cx = (float)x * fs, cy = (float)y * fs;
    float xc = bp[0] * fs + cx;
    float yc = bp[hw] * fs + cy;
    float wv = exp_np(bp[2 * hw]) * fs;
    float hv = exp_np(bp[3 * hw]) * fs;
    float wv2 = wv * 0.5f, hv2 = hv * 0.5f;
    float4 r;
    r.x = xc - wv2;
    r.y = yc - hv2;
    r.z = xc + wv2;
    r.w = yc + hv2;
    return r;
}

// ---------------- Kernel A: per-prior score + np-argmax-over-sigmoids ----------------
__global__ void __launch_bounds__(256) score_k(
    const float* __restrict__ cls0, const float* __restrict__ cls1, const float* __restrict__ cls2,
    const float* __restrict__ ob0,  const float* __restrict__ ob1,  const float* __restrict__ ob2,
    float* __restrict__ sc, int* __restrict__ labels)
{
#pragma clang fp contract(off)
    int gid = blockIdx.x * 256 + threadIdx.x;
    if (gid >= NB * NPRIOR) return;
    int b = gid / NPRIOR;
    int n = gid - b * NPRIOR;
    int W, s, loc; level_of(n, W, s, loc);
    const float* cls = (s == 8) ? cls0 : (s == 16) ? cls1 : cls2;
    const float* ob  = (s == 8) ? ob0  : (s == 16) ? ob1  : ob2;
    int hw = W * W;
    int y = loc / W, x = loc - y * W;

    const float* cp = cls + (size_t)b * NCLS * hw + y * W + x;
    float tM = sigm_np(cp[0]);
    int lab = 0;
    for (int c = 1; c < NCLS; ++c) {
        float t = sigm_np(cp[(size_t)c * hw]);
        if (t > tM) { tM = t; lab = c; }
    }
    float sObj = sigm_np(ob[(size_t)b * hw + y * W + x]);
    float score = tM * sObj;
    bool valid = score >= 0.65f;
    sc[gid] = valid ? score : 0.0f;
    labels[gid] = lab;
}

// ---------------- Kernel B: stable top-K (f32 keys) + f32 decode ----------------
__global__ void __launch_bounds__(256) select_sort(
    const float* __restrict__ sc, const int* __restrict__ labels,
    const float* __restrict__ bb0, const float* __restrict__ bb1, const float* __restrict__ bb2,
    float4* __restrict__ sel_box, float* __restrict__ sel_score,
    int* __restrict__ sel_label, float* __restrict__ mcarr, u64* __restrict__ vmask)
{
#pragma clang fp contract(off)
    __shared__ u64 keys[CAP];
    __shared__ int cnt;
    __shared__ float redbuf[256];
    __shared__ unsigned vbits[32];

    int b = blockIdx.x, tid = threadIdx.x;
    if (tid == 0) cnt = 0;
    if (tid < 32) vbits[tid] = 0u;
    __syncthreads();

    const float* scb = sc + (size_t)b * NPRIOR;
    for (int n = tid; n < NPRIOR; n += 256) {
        float s = scb[n];
        if (s > 0.0f) {
            int p = atomicAdd(&cnt, 1);
            if (p < CAP)
                keys[p] = ((u64)__float_as_uint(s) << 32) | (unsigned)(~(unsigned)n);
        }
    }
    __syncthreads();
    int cn = min(cnt, CAP);
    int S = 1;
    while (S < cn) S <<= 1;
    for (int i = cn + tid; i < S; i += 256) keys[i] = 0ull;
    __syncthreads();

    // bitonic sort desc: score bits desc, index asc (via ~n payload)
    for (int k = 2; k <= S; k <<= 1) {
        for (int j = k >> 1; j > 0; j >>= 1) {
            for (int i = tid; i < S; i += 256) {
                int ixj = i ^ j;
                if (ixj > i) {
                    u64 a = keys[i], c = keys[ixj];
                    bool descB = ((i & k) == 0);
                    if (descB ? (a < c) : (a > c)) { keys[i] = c; keys[ixj] = a; }
                }
            }
            __syncthreads();
        }
    }

    if (cn < KTOP) {
        if (tid == 0) {
            int r = cn;
            for (int n = 0; n < NPRIOR && r < KTOP; ++n) {
                if (scb[n] == 0.0f) { keys[r] = (u64)(unsigned)(~(unsigned)n); ++r; }
            }
        }
        __syncthreads();
    }

    const int* labb = labels + (size_t)b * NPRIOR;
    float lmax = 0.0f;
    for (int kk = tid; kk < 1024; kk += 256) {
        float4 bx = make_float4(0.f, 0.f, 0.f, 0.f);
        float s = 0.0f;
        int lb = 0;
        if (kk < KTOP) {
            u64 key = keys[kk];
            unsigned n = ~(unsigned)(key & 0xffffffffull);
            s = __uint_as_float((unsigned)(key >> 32));
            bx = decode32(b, (int)n, bb0, bb1, bb2);
            lb = labb[n];
            if (s > 0.0f) atomicOr(&vbits[kk >> 5], 1u << (kk & 31));
            lmax = fmaxf(lmax, fmaxf(fmaxf(fabsf(bx.x), fabsf(bx.y)),
                                     fmaxf(fabsf(bx.z), fabsf(bx.w))));
        }
        // pad 1000..1023 with deterministic zeros (excluded from NMS via vmask)
        sel_box[(size_t)b * 1024 + kk] = bx;
        sel_score[(size_t)b * 1024 + kk] = s;
        sel_label[(size_t)b * 1024 + kk] = lb;
    }
    redbuf[tid] = lmax;
    __syncthreads();
    for (int off = 128; off > 0; off >>= 1) {
        if (tid < off) redbuf[tid] = fmaxf(redbuf[tid], redbuf[tid + off]);
        __syncthreads();
    }
    if (tid == 0) mcarr[b] = redbuf[0] + 1.0f;   // max_coord, f32 add
    if (tid < 16)
        vmask[b * 16 + tid] = ((u64)vbits[tid * 2 + 1] << 32) | vbits[tid * 2];
}

// ---------------- Kernel C: TRANSPOSED suppression bitmask via row-ballot ----------------
// Cmask[(b*1024 + col)*16 + rg] : bit j = "row rg*64+j suppresses col" (row < col only)
__global__ void __launch_bounds__(256) build_mask_T(
    const float4* __restrict__ sel_box, const int* __restrict__ sel_label,
    const float* __restrict__ mcarr, u64* __restrict__ Cmask)
{
#pragma clang fp contract(off)
    __shared__ float4 ob[1024];
    __shared__ float ar[1024];
    int b = blockIdx.y, gc = blockIdx.x, tid = threadIdx.x;
    float mc = mcarr[b];
    for (int i = tid; i < 1024; i += 256) {
        float4 v = sel_box[(size_t)b * 1024 + i];
        float off = (float)sel_label[(size_t)b * 1024 + i] * mc;
        v.x += off; v.y += off; v.z += off; v.w += off;
        ob[i] = v;
        ar[i] = (v.z - v.x) * (v.w - v.y);   // area of OFFSET box (as ref)
    }
    __syncthreads();
    int wave = tid >> 6, lane = tid & 63;
#pragma unroll
    for (int rgi = 0; rgi < 4; ++rgi) {
        int rg = wave + rgi * 4;          // row group 0..15
        int row = rg * 64 + lane;
        float4 a = ob[row];
        float aa = ar[row];
        for (int cc = 0; cc < 64; ++cc) {
            int col = gc * 64 + cc;
            bool pred = false;
            if (col > row && row < KTOP && col < KTOP) {
                float4 bb = ob[col];      // broadcast (all lanes same addr)
                float tlx = fmaxf(a.x, bb.x), tly = fmaxf(a.y, bb.y);
                float brx = fminf(a.z, bb.z), bry = fminf(a.w, bb.w);
                float w = fmaxf(brx - tlx, 0.0f), h = fmaxf(bry - tly, 0.0f);
                float inter = w * h;
                float uni = (aa + ar[col]) - inter;
                float iou = inter / (uni + 1e-6f);
                pred = iou > 0.65f;
            }
            u64 bits = __ballot(pred);
            if (lane == 0) Cmask[((size_t)b * 1024 + col) * 16 + rg] = bits;
        }
    }
}

// ---------------- Kernel D: ballot-fixpoint greedy NMS + output ----------------
// One wave per image. Khist is wave-uniform (ballot results) -> SGPRs, fully
// unrolled so all indexing is static (no scratch).
__global__ void __launch_bounds__(64) nms_fixpoint_write(
    const u64* __restrict__ Cmask, const u64* __restrict__ vmask,
    const float4* __restrict__ sel_box, const float* __restrict__ sel_score,
    const int* __restrict__ sel_label, float* __restrict__ out)
{
    int b = blockIdx.x, lane = threadIdx.x;
    const u64* Cimg = Cmask + (size_t)b * 1024 * 16;
    u64 Khist[16];
#pragma unroll
    for (int g = 0; g < 16; ++g) {
        int col = g * 64 + lane;
        const u64* ccol = Cimg + (size_t)col * 16;
        // suppression from earlier (finalized) groups
        bool supp = false;
#pragma unroll
        for (int gp = 0; gp < g; ++gp)
            supp |= (ccol[gp] & Khist[gp]) != 0ull;
        u64 V = vmask[b * 16 + g] & ~__ballot(supp);
        u64 T = ccol[g];                 // in-group suppressors of this col (j<l only)
        // greedy fixpoint: converges in <= chain length (DAG, strict lower bits)
        u64 K = V;
        for (int it = 0; it < 64; ++it) {
            u64 Knew = V & ~__ballot((T & K) != 0ull);
            if (Knew == K) break;        // wave-uniform branch
            K = Knew;
        }
        Khist[g] = K;
    }

    const size_t selo = (size_t)b * 1024;
    float* lab_o = out + (size_t)NB * KTOP * 5;
    float* keep_o = lab_o + (size_t)NB * KTOP;
#pragma unroll
    for (int g = 0; g < 16; ++g) {
        int k = g * 64 + lane;
        if (k >= KTOP) break;
        bool fin = (Khist[g] >> lane) & 1ull;
        float4 bx = sel_box[selo + k];
        float s = sel_score[selo + k];
        int lb = sel_label[selo + k];
        size_t o5 = ((size_t)b * KTOP + k) * 5;
        out[o5 + 0] = fin ? bx.x : 0.0f;
        out[o5 + 1] = fin ? bx.y : 0.0f;
        out[o5 + 2] = fin ? bx.z : 0.0f;
        out[o5 + 3] = fin ? bx.w : 0.0f;
        out[o5 + 4] = fin ? s : 0.0f;
        lab_o[b * KTOP + k] = fin ? (float)lb : -1.0f;
        keep_o[b * KTOP + k] = fin ? 1.0f : 0.0f;
    }
}

extern "C" void kernel_launch(void* const* d_in, const int* in_sizes, int n_in,
                              void* d_out, int out_size, void* d_ws, size_t ws_size,
                              hipStream_t stream) {
    const float* cls0 = (const float*)d_in[0];
    const float* cls1 = (const float*)d_in[1];
    const float* cls2 = (const float*)d_in[2];
    const float* bb0  = (const float*)d_in[3];
    const float* bb1  = (const float*)d_in[4];
    const float* bb2  = (const float*)d_in[5];
    const float* ob0  = (const float*)d_in[6];
    const float* ob1  = (const float*)d_in[7];
    const float* ob2  = (const float*)d_in[8];
    float* out = (float*)d_out;

    char* w = (char*)d_ws;
    size_t used = 0;
    auto alloc = [&](size_t bytes) -> void* {
        void* p = (void*)(w + used);
        used += (bytes + 255) & ~(size_t)255;
        return p;
    };
    float* sc        = (float*)alloc((size_t)NB * NPRIOR * 4);
    int* labels      = (int*)alloc((size_t)NB * NPRIOR * 4);
    float4* sel_box  = (float4*)alloc((size_t)NB * 1024 * 16);
    float* sel_score = (float*)alloc((size_t)NB * 1024 * 4);
    int* sel_label   = (int*)alloc((size_t)NB * 1024 * 4);
    float* mcarr     = (float*)alloc((size_t)NB * 4);
    u64* vmask       = (u64*)alloc((size_t)NB * 16 * 8);
    u64* Cmask       = (u64*)alloc((size_t)NB * 1024 * 16 * 8);

    if (used > ws_size) return;   // OOB-write guard

    int total = NB * NPRIOR;
    score_k<<<(total + 255) / 256, 256, 0, stream>>>(
        cls0, cls1, cls2, ob0, ob1, ob2, sc, labels);
    select_sort<<<NB, 256, 0, stream>>>(
        sc, labels, bb0, bb1, bb2, sel_box, sel_score, sel_label, mcarr, vmask);
    build_mask_T<<<dim3(16, NB), 256, 0, stream>>>(sel_box, sel_label, mcarr, Cmask);
    nms_fixpoint_write<<<NB, 64, 0, stream>>>(
        Cmask, vmask, sel_box, sel_score, sel_label, out);
}

// Round 8
// 176.523 us; speedup vs baseline: 1.6499x; 1.1039x over previous
//
#include <hip/hip_runtime.h>
#include <stdint.h>

#define NPRIOR 8400
#define NB 32
#define NCLS 80
#define KTOP 1000
#define CAP 4096   // max candidates ranked (expected ~1500 valid/image)

typedef unsigned long long u64;

// Bit-exact replica of numpy's float32 SIMD exp (Cephes-style, FMA path).
__device__ __forceinline__ float exp_np(float x) {
#pragma clang fp contract(off)
    if (x > 88.72283935546875f) return __builtin_huge_valf();
    if (x < -87.3365478515625f) return 0.0f;
    float q = rintf(x * 1.442695040f);          // v_rndne: round-nearest-even
    float r = fmaf(q, -6.93145752e-1f, x);      // hi split
    r = fmaf(q, -1.42860677e-6f, r);            // lo split
    float p = fmaf(1.9875691500e-4f, r, 1.3981999507e-3f);
    p = fmaf(p, r, 8.3334519073e-3f);
    p = fmaf(p, r, 4.1665795894e-2f);
    p = fmaf(p, r, 1.6666665459e-1f);
    p = fmaf(p, r, 5.0000001201e-1f);
    float r2 = r * r;
    p = fmaf(p, r2, r);
    p = p + 1.0f;
    return ldexpf(p, (int)q);                   // exact 2^q scaling
}
__device__ __forceinline__ float sigm_np(float x) {
#pragma clang fp contract(off)
    float t = exp_np(-x);
    return 1.0f / (1.0f + t);
}

__device__ __forceinline__ void level_of(int n, int& W, int& s, int& loc) {
    if (n < 6400)      { W = 80; s = 8;  loc = n; }
    else if (n < 8000) { W = 40; s = 16; loc = n - 6400; }
    else               { W = 20; s = 32; loc = n - 8000; }
}

__device__ float4 decode32(int b, int n,
                           const float* bb0, const float* bb1, const float* bb2) {
#pragma clang fp contract(off)
    int W, s, loc; level_of(n, W, s, loc);
    const float* bb = (s == 8) ? bb0 : (s == 16) ? bb1 : bb2;
    int hw = W * W;
    int y = loc / W, x = loc - y * W;
    const float* bp = bb + (size_t)b * 4 * hw + y * W + x;
    float fs = (float)s;
    float cx = (float)x * fs, cy = (float)y * fs;
    float xc = bp[0] * fs + cx;
    float yc = bp[hw] * fs + cy;
    float wv = exp_np(bp[2 * hw]) * fs;
    float hv = exp_np(bp[3 * hw]) * fs;
    float wv2 = wv * 0.5f, hv2 = hv * 0.5f;
    float4 r;
    r.x = xc - wv2;
    r.y = yc - hv2;
    r.z = xc + wv2;
    r.w = yc + hv2;
    return r;
}

// ---------------- Kernel A: per-prior score + np-argmax-over-sigmoids ----------------
__global__ void __launch_bounds__(256) score_k(
    const float* __restrict__ cls0, const float* __restrict__ cls1, const float* __restrict__ cls2,
    const float* __restrict__ ob0,  const float* __restrict__ ob1,  const float* __restrict__ ob2,
    float* __restrict__ sc, int* __restrict__ labels)
{
#pragma clang fp contract(off)
    int gid = blockIdx.x * 256 + threadIdx.x;
    if (gid >= NB * NPRIOR) return;
    int b = gid / NPRIOR;
    int n = gid - b * NPRIOR;
    int W, s, loc; level_of(n, W, s, loc);
    const float* cls = (s == 8) ? cls0 : (s == 16) ? cls1 : cls2;
    const float* ob  = (s == 8) ? ob0  : (s == 16) ? ob1  : ob2;
    int hw = W * W;
    int y = loc / W, x = loc - y * W;

    const float* cp = cls + (size_t)b * NCLS * hw + y * W + x;
    float tM = sigm_np(cp[0]);
    int lab = 0;
    for (int c = 1; c < NCLS; ++c) {
        float t = sigm_np(cp[(size_t)c * hw]);
        if (t > tM) { tM = t; lab = c; }
    }
    float sObj = sigm_np(ob[(size_t)b * hw + y * W + x]);
    float score = tM * sObj;
    bool valid = score >= 0.65f;
    sc[gid] = valid ? score : 0.0f;
    labels[gid] = lab;
}

// ---------------- Kernel B: all-pairs rank top-K (barrier-free scan) ----------------
// rank_i = #{j : key_j > key_i}; keys unique (score bits + ~n) => exact
// permutation identical to stable descending sort. Scatter straight to rank.
__global__ void __launch_bounds__(1024) select_rank(
    const float* __restrict__ sc, const int* __restrict__ labels,
    const float* __restrict__ bb0, const float* __restrict__ bb1, const float* __restrict__ bb2,
    float4* __restrict__ sel_box, float* __restrict__ sel_score,
    int* __restrict__ sel_label, float* __restrict__ mcarr, u64* __restrict__ vmask)
{
#pragma clang fp contract(off)
    __shared__ u64 keys[CAP];
    __shared__ int cnt;
    __shared__ float redbuf[1024];
    __shared__ float lmax_fill;

    int b = blockIdx.x, tid = threadIdx.x;
    if (tid == 0) { cnt = 0; lmax_fill = 0.0f; }
    __syncthreads();

    const float* scb = sc + (size_t)b * NPRIOR;
    for (int n = tid; n < NPRIOR; n += 1024) {
        float s = scb[n];
        if (s > 0.0f) {
            int p = atomicAdd(&cnt, 1);
            if (p < CAP)
                keys[p] = ((u64)__float_as_uint(s) << 32) | (unsigned)(~(unsigned)n);
        }
    }
    __syncthreads();
    int cn = min(cnt, CAP);

    const int* labb = labels + (size_t)b * NPRIOR;
    float lmax = 0.0f;
    for (int i = tid; i < cn; i += 1024) {
        u64 ki = keys[i];
        int rank = 0;
        // all lanes read the same keys[j] each iteration -> LDS broadcast
        int j = 0;
        for (; j + 4 <= cn; j += 4) {
            rank += (keys[j]     > ki);
            rank += (keys[j + 1] > ki);
            rank += (keys[j + 2] > ki);
            rank += (keys[j + 3] > ki);
        }
        for (; j < cn; ++j) rank += (keys[j] > ki);
        if (rank < KTOP) {
            unsigned n = ~(unsigned)(ki & 0xffffffffull);
            float s = __uint_as_float((unsigned)(ki >> 32));
            float4 bx = decode32(b, (int)n, bb0, bb1, bb2);
            sel_box[(size_t)b * 1024 + rank] = bx;
            sel_score[(size_t)b * 1024 + rank] = s;
            sel_label[(size_t)b * 1024 + rank] = labb[n];
            lmax = fmaxf(lmax, fmaxf(fmaxf(fabsf(bx.x), fabsf(bx.y)),
                                     fmaxf(fabsf(bx.z), fabsf(bx.w))));
        }
    }

    // rare path: fewer than K valid -> fill remaining slots with lowest-index
    // zero-score entries (top_k stable order among equal zeros)
    if (cn < KTOP && tid == 0) {
        float lm = 0.0f;
        int r = cn;
        for (int n = 0; n < NPRIOR && r < KTOP; ++n) {
            if (scb[n] == 0.0f) {
                float4 bx = decode32(b, n, bb0, bb1, bb2);
                sel_box[(size_t)b * 1024 + r] = bx;
                sel_score[(size_t)b * 1024 + r] = 0.0f;
                sel_label[(size_t)b * 1024 + r] = labb[n];
                lm = fmaxf(lm, fmaxf(fmaxf(fabsf(bx.x), fabsf(bx.y)),
                                     fmaxf(fabsf(bx.z), fabsf(bx.w))));
                ++r;
            }
        }
        lmax_fill = lm;
    }

    // padding rows 1000..1023: deterministic zeros (excluded via vmask)
    if (tid >= 1000 && tid < 1024) {
        sel_box[(size_t)b * 1024 + tid] = make_float4(0.f, 0.f, 0.f, 0.f);
        sel_score[(size_t)b * 1024 + tid] = 0.0f;
        sel_label[(size_t)b * 1024 + tid] = 0;
    }

    redbuf[tid] = lmax;
    __syncthreads();
    for (int off = 512; off > 0; off >>= 1) {
        if (tid < off) redbuf[tid] = fmaxf(redbuf[tid], redbuf[tid + off]);
        __syncthreads();
    }
    if (tid == 0) mcarr[b] = fmaxf(redbuf[0], lmax_fill) + 1.0f;

    // vmask: first min(cn,KTOP) positions valid, rest invalid (closed form)
    if (tid < 16) {
        int vc = min(cn, KTOP);
        int lo = tid * 64;
        u64 m;
        if (vc >= lo + 64)      m = ~0ull;
        else if (vc <= lo)      m = 0ull;
        else                    m = (1ull << (vc - lo)) - 1ull;
        vmask[b * 16 + tid] = m;
    }
}

// ---------------- Kernel C: TRANSPOSED suppression bitmask via row-ballot ----------------
// Cmask[(b*1024 + col)*16 + rg] : bit j = "row rg*64+j suppresses col" (row < col only)
__global__ void __launch_bounds__(256) build_mask_T(
    const float4* __restrict__ sel_box, const int* __restrict__ sel_label,
    const float* __restrict__ mcarr, u64* __restrict__ Cmask)
{
#pragma clang fp contract(off)
    __shared__ float4 ob[1024];
    __shared__ float ar[1024];
    int b = blockIdx.y, gc = blockIdx.x, tid = threadIdx.x;
    float mc = mcarr[b];
    for (int i = tid; i < 1024; i += 256) {
        float4 v = sel_box[(size_t)b * 1024 + i];
        float off = (float)sel_label[(size_t)b * 1024 + i] * mc;
        v.x += off; v.y += off; v.z += off; v.w += off;
        ob[i] = v;
        ar[i] = (v.z - v.x) * (v.w - v.y);   // area of OFFSET box (as ref)
    }
    __syncthreads();
    int wave = tid >> 6, lane = tid & 63;
#pragma unroll
    for (int rgi = 0; rgi < 4; ++rgi) {
        int rg = wave + rgi * 4;          // row group 0..15
        int row = rg * 64 + lane;
        float4 a = ob[row];
        float aa = ar[row];
        for (int cc = 0; cc < 64; ++cc) {
            int col = gc * 64 + cc;
            bool pred = false;
            if (col > row && row < KTOP && col < KTOP) {
                float4 bb = ob[col];      // broadcast (all lanes same addr)
                float tlx = fmaxf(a.x, bb.x), tly = fmaxf(a.y, bb.y);
                float brx = fminf(a.z, bb.z), bry = fminf(a.w, bb.w);
                float w = fmaxf(brx - tlx, 0.0f), h = fmaxf(bry - tly, 0.0f);
                float inter = w * h;
                float uni = (aa + ar[col]) - inter;
                float iou = inter / (uni + 1e-6f);
                pred = iou > 0.65f;
            }
            u64 bits = __ballot(pred);
            if (lane == 0) Cmask[((size_t)b * 1024 + col) * 16 + rg] = bits;
        }
    }
}

// ---------------- Kernel D: ballot-fixpoint greedy NMS + output ----------------
__global__ void __launch_bounds__(64) nms_fixpoint_write(
    const u64* __restrict__ Cmask, const u64* __restrict__ vmask,
    const float4* __restrict__ sel_box, const float* __restrict__ sel_score,
    const int* __restrict__ sel_label, float* __restrict__ out)
{
    int b = blockIdx.x, lane = threadIdx.x;
    const u64* Cimg = Cmask + (size_t)b * 1024 * 16;
    u64 Khist[16];
#pragma unroll
    for (int g = 0; g < 16; ++g) {
        int col = g * 64 + lane;
        const u64* ccol = Cimg + (size_t)col * 16;
        bool supp = false;
#pragma unroll
        for (int gp = 0; gp < g; ++gp)
            supp |= (ccol[gp] & Khist[gp]) != 0ull;
        u64 V = vmask[b * 16 + g] & ~__ballot(supp);
        u64 T = ccol[g];
        u64 K = V;
        for (int it = 0; it < 64; ++it) {
            u64 Knew = V & ~__ballot((T & K) != 0ull);
            if (Knew == K) break;        // wave-uniform branch
            K = Knew;
        }
        Khist[g] = K;
    }

    const size_t selo = (size_t)b * 1024;
    float* lab_o = out + (size_t)NB * KTOP * 5;
    float* keep_o = lab_o + (size_t)NB * KTOP;
#pragma unroll
    for (int g = 0; g < 16; ++g) {
        int k = g * 64 + lane;
        if (k >= KTOP) break;
        bool fin = (Khist[g] >> lane) & 1ull;
        float4 bx = sel_box[selo + k];
        float s = sel_score[selo + k];
        int lb = sel_label[selo + k];
        size_t o5 = ((size_t)b * KTOP + k) * 5;
        out[o5 + 0] = fin ? bx.x : 0.0f;
        out[o5 + 1] = fin ? bx.y : 0.0f;
        out[o5 + 2] = fin ? bx.z : 0.0f;
        out[o5 + 3] = fin ? bx.w : 0.0f;
        out[o5 + 4] = fin ? s : 0.0f;
        lab_o[b * KTOP + k] = fin ? (float)lb : -1.0f;
        keep_o[b * KTOP + k] = fin ? 1.0f : 0.0f;
    }
}

extern "C" void kernel_launch(void* const* d_in, const int* in_sizes, int n_in,
                              void* d_out, int out_size, void* d_ws, size_t ws_size,
                              hipStream_t stream) {
    const float* cls0 = (const float*)d_in[0];
    const float* cls1 = (const float*)d_in[1];
    const float* cls2 = (const float*)d_in[2];
    const float* bb0  = (const float*)d_in[3];
    const float* bb1  = (const float*)d_in[4];
    const float* bb2  = (const float*)d_in[5];
    const float* ob0  = (const float*)d_in[6];
    const float* ob1  = (const float*)d_in[7];
    const float* ob2  = (const float*)d_in[8];
    float* out = (float*)d_out;

    char* w = (char*)d_ws;
    size_t used = 0;
    auto alloc = [&](size_t bytes) -> void* {
        void* p = (void*)(w + used);
        used += (bytes + 255) & ~(size_t)255;
        return p;
    };
    float* sc        = (float*)alloc((size_t)NB * NPRIOR * 4);
    int* labels      = (int*)alloc((size_t)NB * NPRIOR * 4);
    float4* sel_box  = (float4*)alloc((size_t)NB * 1024 * 16);
    float* sel_score = (float*)alloc((size_t)NB * 1024 * 4);
    int* sel_label   = (int*)alloc((size_t)NB * 1024 * 4);
    float* mcarr     = (float*)alloc((size_t)NB * 4);
    u64* vmask       = (u64*)alloc((size_t)NB * 16 * 8);
    u64* Cmask       = (u64*)alloc((size_t)NB * 1024 * 16 * 8);

    if (used > ws_size) return;   // OOB-write guard

    int total = NB * NPRIOR;
    score_k<<<(total + 255) / 256, 256, 0, stream>>>(
        cls0, cls1, cls2, ob0, ob1, ob2, sc, labels);
    select_rank<<<NB, 1024, 0, stream>>>(
        sc, labels, bb0, bb1, bb2, sel_box, sel_score, sel_label, mcarr, vmask);
    build_mask_T<<<dim3(16, NB), 256, 0, stream>>>(sel_box, sel_label, mcarr, Cmask);
    nms_fixpoint_write<<<NB, 64, 0, stream>>>(
        Cmask, vmask, sel_box, sel_score, sel_label, out);
}